// Round 1
// baseline (550.516 us; speedup 1.0000x reference)
//
#include <hip/hip_runtime.h>
#include <math.h>

#define HID 128

// ---------------- embedding: h0 = relu(key_emb[f0] + val_emb[f1]) ----------
__global__ __launch_bounds__(256) void embed_kernel(
    const int* __restrict__ feats, const float* __restrict__ ke,
    const float* __restrict__ ve, float* __restrict__ h, int N) {
  int gid = blockIdx.x * 256 + threadIdx.x;
  int n = gid >> 5, j = gid & 31;           // 32 float4 chunks per node
  if (n >= N) return;
  int i0 = feats[2 * n];
  int i1 = feats[2 * n + 1];
  float4 a = ((const float4*)(ke + (size_t)i0 * HID))[j];
  float4 b = ((const float4*)(ve + (size_t)i1 * HID))[j];
  float4 r;
  r.x = fmaxf(a.x + b.x, 0.f);
  r.y = fmaxf(a.y + b.y, 0.f);
  r.z = fmaxf(a.z + b.z, 0.f);
  r.w = fmaxf(a.w + b.w, 0.f);
  ((float4*)(h + (size_t)n * HID))[j] = r;
}

// ---------------- CSR build -------------------------------------------------
__global__ __launch_bounds__(256) void hist_kernel(
    const int* __restrict__ dst, int* __restrict__ counts, int E) {
  int e = blockIdx.x * 256 + threadIdx.x;
  if (e < E) atomicAdd(&counts[dst[e]], 1);
}

__global__ __launch_bounds__(1024) void scan_kernel(
    const int* __restrict__ counts, int* __restrict__ offs, int N) {
  __shared__ int part[1024];
  int t = threadIdx.x;
  int chunk = (N + 1023) / 1024;
  int start = t * chunk;
  int end = min(start + chunk, N);
  int s = 0;
  for (int i = start; i < end; ++i) s += counts[i];
  part[t] = s;
  __syncthreads();
  for (int off = 1; off < 1024; off <<= 1) {
    int v = (t >= off) ? part[t - off] : 0;
    __syncthreads();
    part[t] += v;
    __syncthreads();
  }
  int run = (t > 0) ? part[t - 1] : 0;   // exclusive base
  for (int i = start; i < end; ++i) { offs[i] = run; run += counts[i]; }
  if (start < N && start + chunk >= N) offs[N] = run;
}

__global__ __launch_bounds__(256) void scatter_kernel(
    const int* __restrict__ src, const int* __restrict__ dst,
    const int* __restrict__ offs, int* __restrict__ cursor,
    int* __restrict__ csr, int E) {
  int e = blockIdx.x * 256 + threadIdx.x;
  if (e >= E) return;
  int d = dst[e];
  int pos = offs[d] + atomicAdd(&cursor[d], 1);
  csr[pos] = src[e];
}

// ---------------- GEMM: F[N,128] = H[N,128] @ W[128,128] -------------------
__global__ __launch_bounds__(256) void gemm_kernel(
    const float* __restrict__ H, const float* __restrict__ W,
    float* __restrict__ F, int N) {
  __shared__ float4 sW4[128 * 32];   // W as [k][col/4], 64 KB
  __shared__ float sH[8][128];       // 8 rows staged, 4 KB
  const float4* W4 = (const float4*)W;
  for (int i = threadIdx.x; i < 128 * 32; i += 256) sW4[i] = W4[i];
  int row0 = blockIdx.x * 8;
  {
    int r = threadIdx.x >> 5;
    int j = threadIdx.x & 31;
    int row = min(row0 + r, N - 1);
    ((float4*)&sH[r][0])[j] = ((const float4*)(H + (size_t)row * HID))[j];
  }
  __syncthreads();
  int r = threadIdx.x >> 5;    // row within block, 0..7
  int cg = threadIdx.x & 31;   // col group of 4
  float4 acc = make_float4(0.f, 0.f, 0.f, 0.f);
#pragma unroll 4
  for (int k = 0; k < 128; ++k) {
    float hv = sH[r][k];                 // broadcast (same addr per half-wave)
    float4 wv = sW4[k * 32 + cg];
    acc.x += hv * wv.x;
    acc.y += hv * wv.y;
    acc.z += hv * wv.z;
    acc.w += hv * wv.w;
  }
  int row = row0 + r;
  if (row < N) ((float4*)(F + (size_t)row * HID))[cg] = acc;
}

// ---------------- GATv2 layer: online-softmax aggregate per dst node -------
// one wave (64 lanes) per node; lane holds components 2*lane, 2*lane+1
__global__ __launch_bounds__(256) void gat_kernel(
    const float* __restrict__ F, const int* __restrict__ offs,
    const int* __restrict__ csr, const float* __restrict__ attn,
    float* __restrict__ Hout, int N) {
  int node = blockIdx.x * 4 + (threadIdx.x >> 6);
  int lane = threadIdx.x & 63;
  if (node >= N) return;
  int beg = offs[node];
  int end = offs[node + 1];
  const float2* F2 = (const float2*)F;
  float2 fd = F2[(size_t)node * 64 + lane];
  float a0 = attn[lane * 2];
  float a1 = attn[lane * 2 + 1];
  float m = -INFINITY, l = 0.f, acc0 = 0.f, acc1 = 0.f;
  for (int i = beg; i < end; ++i) {
    int s = csr[i];                        // wave-uniform
    float2 fs = F2[(size_t)s * 64 + lane]; // 512 B contiguous per wave
    float t0 = fs.x + fd.x;
    float t1 = fs.y + fd.y;
    t0 = fmaxf(t0, 0.f) + 0.2f * fminf(t0, 0.f);   // leaky_relu
    t1 = fmaxf(t1, 0.f) + 0.2f * fminf(t1, 0.f);
    float p = a0 * t0 + a1 * t1;
#pragma unroll
    for (int o = 32; o > 0; o >>= 1) p += __shfl_xor(p, o, 64);
    float mn = fmaxf(m, p);
    float sc = __expf(m - mn);             // m=-inf first iter -> 0
    float ex = __expf(p - mn);
    l = l * sc + ex;
    acc0 = acc0 * sc + ex * fs.x;
    acc1 = acc1 * sc + ex * fs.y;
    m = mn;
  }
  float inv = (l > 0.f) ? 1.f / l : 0.f;
  float2 o2;
  o2.x = acc0 * inv;
  o2.y = acc1 * inv;
  ((float2*)Hout)[(size_t)node * 64 + lane] = o2;
}

// ---------------- classifier: out[N,OUT] = H @ cls_w -----------------------
__global__ __launch_bounds__(256) void classify_kernel(
    const float* __restrict__ H, const float* __restrict__ Wc,
    float* __restrict__ out, int N, int OUTD) {
  extern __shared__ float sW[];
  for (int i = threadIdx.x; i < HID * OUTD; i += 256) sW[i] = Wc[i];
  __syncthreads();
  int idx = blockIdx.x * 256 + threadIdx.x;
  int n = idx / OUTD;
  int c = idx % OUTD;
  if (n >= N) return;
  const float4* h4 = (const float4*)(H + (size_t)n * HID);
  float acc = 0.f;
#pragma unroll 8
  for (int kk = 0; kk < 32; ++kk) {
    float4 hv = h4[kk];
    acc += hv.x * sW[(kk * 4 + 0) * OUTD + c];
    acc += hv.y * sW[(kk * 4 + 1) * OUTD + c];
    acc += hv.z * sW[(kk * 4 + 2) * OUTD + c];
    acc += hv.w * sW[(kk * 4 + 3) * OUTD + c];
  }
  out[idx] = acc;
}

// ---------------------------------------------------------------------------
extern "C" void kernel_launch(void* const* d_in, const int* in_sizes, int n_in,
                              void* d_out, int out_size, void* d_ws, size_t ws_size,
                              hipStream_t stream) {
  const int* feats    = (const int*)d_in[0];
  const int* src      = (const int*)d_in[1];
  const int* dst      = (const int*)d_in[2];
  const float* key_emb = (const float*)d_in[3];
  const float* val_emb = (const float*)d_in[4];
  const float* W1     = (const float*)d_in[5];
  const float* attn1  = (const float*)d_in[6];
  const float* W2     = (const float*)d_in[7];
  const float* attn2  = (const float*)d_in[8];
  const float* cls_w  = (const float*)d_in[9];

  int N = in_sizes[0] / 2;
  int E = in_sizes[1];
  int OUTD = in_sizes[9] / HID;

  // workspace layout
  char* ws = (char*)d_ws;
  float* fbuf = (float*)ws;                         // N*128 f32 (transformed feats)
  float* hbuf = fbuf + (size_t)N * HID;             // N*128 f32 (node states)
  int* counts = (int*)(hbuf + (size_t)N * HID);     // N
  int* cursor = counts + N;                         // N
  int* offs   = cursor + N;                         // N+1
  int* csr    = offs + (N + 1);                     // E

  hipMemsetAsync(counts, 0, sizeof(int) * 2 * (size_t)N, stream);  // counts+cursor

  embed_kernel<<<(N * 32 + 255) / 256, 256, 0, stream>>>(feats, key_emb, val_emb, hbuf, N);
  hist_kernel<<<(E + 255) / 256, 256, 0, stream>>>(dst, counts, E);
  scan_kernel<<<1, 1024, 0, stream>>>(counts, offs, N);
  scatter_kernel<<<(E + 255) / 256, 256, 0, stream>>>(src, dst, offs, cursor, csr, E);

  // layer 1
  gemm_kernel<<<(N + 7) / 8, 256, 0, stream>>>(hbuf, W1, fbuf, N);
  gat_kernel<<<(N + 3) / 4, 256, 0, stream>>>(fbuf, offs, csr, attn1, hbuf, N);
  // layer 2
  gemm_kernel<<<(N + 7) / 8, 256, 0, stream>>>(hbuf, W2, fbuf, N);
  gat_kernel<<<(N + 3) / 4, 256, 0, stream>>>(fbuf, offs, csr, attn2, hbuf, N);

  classify_kernel<<<((size_t)N * OUTD + 255) / 256, 256,
                    HID * OUTD * sizeof(float), stream>>>(hbuf, cls_w, (float*)d_out, N, OUTD);
}

// Round 2
// 320.440 us; speedup vs baseline: 1.7180x; 1.7180x over previous
//
#include <hip/hip_runtime.h>
#include <math.h>

#define HID 128

// ---------------- CSR build -------------------------------------------------
__global__ __launch_bounds__(256) void hist_kernel(
    const int* __restrict__ dst, int* __restrict__ counts, int E) {
  int e = blockIdx.x * 256 + threadIdx.x;
  if (e < E) atomicAdd(&counts[dst[e]], 1);
}

// block b sums counts[b*256 .. b*256+255] -> partials[b]
__global__ __launch_bounds__(256) void partial_kernel(
    const int* __restrict__ counts, int* __restrict__ partials, int N) {
  __shared__ int s[256];
  int idx = blockIdx.x * 256 + threadIdx.x;
  s[threadIdx.x] = (idx < N) ? counts[idx] : 0;
  __syncthreads();
  for (int o = 128; o > 0; o >>= 1) {
    if (threadIdx.x < o) s[threadIdx.x] += s[threadIdx.x + o];
    __syncthreads();
  }
  if (threadIdx.x == 0) partials[blockIdx.x] = s[0];
}

// single block: exclusive-scan 256 partials -> bases
__global__ __launch_bounds__(256) void scan2_kernel(
    const int* __restrict__ partials, int* __restrict__ bases, int NB) {
  __shared__ int s[256];
  int t = threadIdx.x;
  int v0 = (t < NB) ? partials[t] : 0;
  s[t] = v0;
  __syncthreads();
  for (int o = 1; o < 256; o <<= 1) {
    int v = (t >= o) ? s[t - o] : 0;
    __syncthreads();
    s[t] += v;
    __syncthreads();
  }
  bases[t] = s[t] - v0;   // exclusive
}

// block b: exclusive scan of its 256 counts + base -> offs; last writes offs[N]
__global__ __launch_bounds__(256) void offs_kernel(
    const int* __restrict__ counts, const int* __restrict__ bases,
    int* __restrict__ offs, int N) {
  __shared__ int s[256];
  int t = threadIdx.x;
  int idx = blockIdx.x * 256 + t;
  int c = (idx < N) ? counts[idx] : 0;
  s[t] = c;
  __syncthreads();
  for (int o = 1; o < 256; o <<= 1) {
    int v = (t >= o) ? s[t - o] : 0;
    __syncthreads();
    s[t] += v;
    __syncthreads();
  }
  int base = bases[blockIdx.x];
  if (idx < N) offs[idx] = base + s[t] - c;
  if (idx == N - 1) offs[N] = base + s[t];
}

__global__ __launch_bounds__(256) void scatter_kernel(
    const int* __restrict__ src, const int* __restrict__ dst,
    const int* __restrict__ offs, int* __restrict__ cursor,
    int* __restrict__ csr, int E) {
  int e = blockIdx.x * 256 + threadIdx.x;
  if (e >= E) return;
  int d = dst[e];
  int pos = offs[d] + atomicAdd(&cursor[d], 1);
  csr[pos] = src[e];
}

// ---------------- GEMM: F[N,128] = H[N,128] @ W[128,128] -------------------
// 32 rows/block, 256 threads; thread computes 4 rows x 4 cols.
// FUSE_EMBED: rows come from relu(ke[f0]+ve[f1]) instead of H.
template <bool FUSE_EMBED>
__global__ __launch_bounds__(256) void gemm_kernel(
    const float* __restrict__ H, const int* __restrict__ feats,
    const float* __restrict__ ke, const float* __restrict__ ve,
    const float* __restrict__ W, float* __restrict__ F, int N) {
  __shared__ float4 sW4[128 * 32];   // 64 KB
  __shared__ float sH[32][128];      // 16 KB  (total 80 KB -> 2 blocks/CU)
  const float4* W4 = (const float4*)W;
  for (int i = threadIdx.x; i < 128 * 32; i += 256) sW4[i] = W4[i];
  int row0 = blockIdx.x * 32;
  for (int i = threadIdx.x; i < 32 * 32; i += 256) {
    int r = i >> 5, j = i & 31;
    int row = row0 + r;
    float4 v = make_float4(0.f, 0.f, 0.f, 0.f);
    if (row < N) {
      if (FUSE_EMBED) {
        int f0 = feats[2 * row], f1 = feats[2 * row + 1];
        float4 a = ((const float4*)(ke + (size_t)f0 * HID))[j];
        float4 b = ((const float4*)(ve + (size_t)f1 * HID))[j];
        v.x = fmaxf(a.x + b.x, 0.f);
        v.y = fmaxf(a.y + b.y, 0.f);
        v.z = fmaxf(a.z + b.z, 0.f);
        v.w = fmaxf(a.w + b.w, 0.f);
      } else {
        v = ((const float4*)(H + (size_t)row * HID))[j];
      }
    }
    ((float4*)&sH[r][0])[j] = v;
  }
  __syncthreads();
  int rg = threadIdx.x >> 5;   // 0..7 -> rows rg*4..rg*4+3
  int cg = threadIdx.x & 31;   // col group of 4
  float4 acc0 = make_float4(0.f, 0.f, 0.f, 0.f);
  float4 acc1 = acc0, acc2 = acc0, acc3 = acc0;
#pragma unroll 4
  for (int k = 0; k < 128; ++k) {
    float4 wv = sW4[k * 32 + cg];
    float h0 = sH[rg * 4 + 0][k];   // broadcast per half-wave (2-way: free)
    float h1 = sH[rg * 4 + 1][k];
    float h2 = sH[rg * 4 + 2][k];
    float h3 = sH[rg * 4 + 3][k];
    acc0.x += h0 * wv.x; acc0.y += h0 * wv.y; acc0.z += h0 * wv.z; acc0.w += h0 * wv.w;
    acc1.x += h1 * wv.x; acc1.y += h1 * wv.y; acc1.z += h1 * wv.z; acc1.w += h1 * wv.w;
    acc2.x += h2 * wv.x; acc2.y += h2 * wv.y; acc2.z += h2 * wv.z; acc2.w += h2 * wv.w;
    acc3.x += h3 * wv.x; acc3.y += h3 * wv.y; acc3.z += h3 * wv.z; acc3.w += h3 * wv.w;
  }
  int r0 = row0 + rg * 4;
  if (r0 + 0 < N) ((float4*)(F + (size_t)(r0 + 0) * HID))[cg] = acc0;
  if (r0 + 1 < N) ((float4*)(F + (size_t)(r0 + 1) * HID))[cg] = acc1;
  if (r0 + 2 < N) ((float4*)(F + (size_t)(r0 + 2) * HID))[cg] = acc2;
  if (r0 + 3 < N) ((float4*)(F + (size_t)(r0 + 3) * HID))[cg] = acc3;
}

// ---------------- GATv2 layer: online-softmax aggregate, 4-edge unroll -----
__device__ __forceinline__ float edge_partial(float2 fs, float2 fd, float a0, float a1) {
  float t0 = fs.x + fd.x;
  float t1 = fs.y + fd.y;
  t0 = fmaxf(t0, 0.f) + 0.2f * fminf(t0, 0.f);
  t1 = fmaxf(t1, 0.f) + 0.2f * fminf(t1, 0.f);
  return a0 * t0 + a1 * t1;
}

__global__ __launch_bounds__(256) void gat_kernel(
    const float* __restrict__ F, const int* __restrict__ offs,
    const int* __restrict__ csr, const float* __restrict__ attn,
    float* __restrict__ Hout, int N) {
  int node = blockIdx.x * 4 + (threadIdx.x >> 6);
  int lane = threadIdx.x & 63;
  if (node >= N) return;
  int beg = offs[node];
  int end = offs[node + 1];
  const float2* F2 = (const float2*)F;
  float2 fd = F2[(size_t)node * 64 + lane];
  float2 av = ((const float2*)attn)[lane];
  float a0 = av.x, a1 = av.y;
  float m = -INFINITY, l = 0.f, acc0 = 0.f, acc1 = 0.f;
  int i = beg;
  for (; i + 4 <= end; i += 4) {
    int s0 = csr[i + 0];
    int s1 = csr[i + 1];
    int s2 = csr[i + 2];
    int s3 = csr[i + 3];
    float2 f0 = F2[(size_t)s0 * 64 + lane];
    float2 f1 = F2[(size_t)s1 * 64 + lane];
    float2 f2 = F2[(size_t)s2 * 64 + lane];
    float2 f3 = F2[(size_t)s3 * 64 + lane];
    float p0 = edge_partial(f0, fd, a0, a1);
    float p1 = edge_partial(f1, fd, a0, a1);
    float p2 = edge_partial(f2, fd, a0, a1);
    float p3 = edge_partial(f3, fd, a0, a1);
#pragma unroll
    for (int o = 32; o > 0; o >>= 1) {
      p0 += __shfl_xor(p0, o, 64);
      p1 += __shfl_xor(p1, o, 64);
      p2 += __shfl_xor(p2, o, 64);
      p3 += __shfl_xor(p3, o, 64);
    }
    float m4 = fmaxf(fmaxf(p0, p1), fmaxf(p2, p3));
    float mn = fmaxf(m, m4);
    float sc = __expf(m - mn);          // first iter: exp(-inf)=0
    float e0 = __expf(p0 - mn);
    float e1 = __expf(p1 - mn);
    float e2 = __expf(p2 - mn);
    float e3 = __expf(p3 - mn);
    l = l * sc + ((e0 + e1) + (e2 + e3));
    acc0 = acc0 * sc + ((e0 * f0.x + e1 * f1.x) + (e2 * f2.x + e3 * f3.x));
    acc1 = acc1 * sc + ((e0 * f0.y + e1 * f1.y) + (e2 * f2.y + e3 * f3.y));
    m = mn;
  }
  for (; i < end; ++i) {
    int s = csr[i];
    float2 fs = F2[(size_t)s * 64 + lane];
    float p = edge_partial(fs, fd, a0, a1);
#pragma unroll
    for (int o = 32; o > 0; o >>= 1) p += __shfl_xor(p, o, 64);
    float mn = fmaxf(m, p);
    float sc = __expf(m - mn);
    float ex = __expf(p - mn);
    l = l * sc + ex;
    acc0 = acc0 * sc + ex * fs.x;
    acc1 = acc1 * sc + ex * fs.y;
    m = mn;
  }
  float inv = (l > 0.f) ? 1.f / l : 0.f;
  float2 o2;
  o2.x = acc0 * inv;
  o2.y = acc1 * inv;
  ((float2*)Hout)[(size_t)node * 64 + lane] = o2;
}

// ---------------- classifier: out[N,16] = H @ cls_w ------------------------
__global__ __launch_bounds__(256) void classify_kernel(
    const float* __restrict__ H, const float* __restrict__ Wc,
    float* __restrict__ out, int N) {
  __shared__ float sW[HID * 16];     // 8 KB
  __shared__ float sH[16][132];      // padded: reads spread over banks
  for (int i = threadIdx.x; i < HID * 16; i += 256) sW[i] = Wc[i];
  int row0 = blockIdx.x * 16;
  for (int i = threadIdx.x; i < 16 * 32; i += 256) {
    int r = i >> 5, j = i & 31;
    int row = row0 + r;
    float4 v = make_float4(0.f, 0.f, 0.f, 0.f);
    if (row < N) v = ((const float4*)(H + (size_t)row * HID))[j];
    ((float4*)&sH[r][0])[j] = v;
  }
  __syncthreads();
  int r = threadIdx.x >> 4;   // 0..15
  int c = threadIdx.x & 15;   // 0..15
  float acc = 0.f;
#pragma unroll 8
  for (int k = 0; k < HID; ++k) acc += sH[r][k] * sW[k * 16 + c];
  int row = row0 + r;
  if (row < N) out[(size_t)row * 16 + c] = acc;
}

// ---------------------------------------------------------------------------
extern "C" void kernel_launch(void* const* d_in, const int* in_sizes, int n_in,
                              void* d_out, int out_size, void* d_ws, size_t ws_size,
                              hipStream_t stream) {
  const int* feats     = (const int*)d_in[0];
  const int* src       = (const int*)d_in[1];
  const int* dst       = (const int*)d_in[2];
  const float* key_emb = (const float*)d_in[3];
  const float* val_emb = (const float*)d_in[4];
  const float* W1      = (const float*)d_in[5];
  const float* attn1   = (const float*)d_in[6];
  const float* W2      = (const float*)d_in[7];
  const float* attn2   = (const float*)d_in[8];
  const float* cls_w   = (const float*)d_in[9];

  int N = in_sizes[0] / 2;
  int E = in_sizes[1];
  int NB = (N + 255) / 256;   // <= 256 assumed (N <= 65536)

  // workspace layout
  char* ws = (char*)d_ws;
  float* fbuf  = (float*)ws;                        // N*128 f32
  float* hbuf  = fbuf + (size_t)N * HID;            // N*128 f32
  int* counts  = (int*)(hbuf + (size_t)N * HID);    // N
  int* cursor  = counts + N;                        // N
  int* offs    = cursor + N;                        // N+1
  int* csr     = offs + (N + 1);                    // E
  int* partials = csr + E;                          // 256
  int* bases    = partials + 256;                   // 256

  hipMemsetAsync(counts, 0, sizeof(int) * 2 * (size_t)N, stream);  // counts+cursor

  hist_kernel<<<(E + 255) / 256, 256, 0, stream>>>(dst, counts, E);
  partial_kernel<<<NB, 256, 0, stream>>>(counts, partials, N);
  scan2_kernel<<<1, 256, 0, stream>>>(partials, bases, NB);
  offs_kernel<<<NB, 256, 0, stream>>>(counts, bases, offs, N);
  scatter_kernel<<<(E + 255) / 256, 256, 0, stream>>>(src, dst, offs, cursor, csr, E);

  // layer 1 (embed fused into GEMM staging)
  gemm_kernel<true><<<(N + 31) / 32, 256, 0, stream>>>(
      nullptr, feats, key_emb, val_emb, W1, fbuf, N);
  gat_kernel<<<(N + 3) / 4, 256, 0, stream>>>(fbuf, offs, csr, attn1, hbuf, N);
  // layer 2
  gemm_kernel<false><<<(N + 31) / 32, 256, 0, stream>>>(
      hbuf, nullptr, nullptr, nullptr, W2, fbuf, N);
  gat_kernel<<<(N + 3) / 4, 256, 0, stream>>>(fbuf, offs, csr, attn2, hbuf, N);

  classify_kernel<<<(N + 15) / 16, 256, 0, stream>>>(hbuf, cls_w, (float*)d_out, N);
}

// Round 3
// 313.980 us; speedup vs baseline: 1.7533x; 1.0206x over previous
//
#include <hip/hip_runtime.h>
#include <math.h>

#define HID 128

// ---------------- CSR build -------------------------------------------------
__global__ __launch_bounds__(256) void hist_kernel(
    const int* __restrict__ dst, int* __restrict__ counts, int E) {
  int e = blockIdx.x * 256 + threadIdx.x;
  if (e < E) atomicAdd(&counts[dst[e]], 1);
}

__global__ __launch_bounds__(256) void partial_kernel(
    const int* __restrict__ counts, int* __restrict__ partials, int N) {
  __shared__ int s[256];
  int idx = blockIdx.x * 256 + threadIdx.x;
  s[threadIdx.x] = (idx < N) ? counts[idx] : 0;
  __syncthreads();
  for (int o = 128; o > 0; o >>= 1) {
    if (threadIdx.x < o) s[threadIdx.x] += s[threadIdx.x + o];
    __syncthreads();
  }
  if (threadIdx.x == 0) partials[blockIdx.x] = s[0];
}

__global__ __launch_bounds__(256) void scan2_kernel(
    const int* __restrict__ partials, int* __restrict__ bases, int NB) {
  __shared__ int s[256];
  int t = threadIdx.x;
  int v0 = (t < NB) ? partials[t] : 0;
  s[t] = v0;
  __syncthreads();
  for (int o = 1; o < 256; o <<= 1) {
    int v = (t >= o) ? s[t - o] : 0;
    __syncthreads();
    s[t] += v;
    __syncthreads();
  }
  bases[t] = s[t] - v0;   // exclusive
}

__global__ __launch_bounds__(256) void offs_kernel(
    const int* __restrict__ counts, const int* __restrict__ bases,
    int* __restrict__ offs, int N) {
  __shared__ int s[256];
  int t = threadIdx.x;
  int idx = blockIdx.x * 256 + t;
  int c = (idx < N) ? counts[idx] : 0;
  s[t] = c;
  __syncthreads();
  for (int o = 1; o < 256; o <<= 1) {
    int v = (t >= o) ? s[t - o] : 0;
    __syncthreads();
    s[t] += v;
    __syncthreads();
  }
  int base = bases[blockIdx.x];
  if (idx < N) offs[idx] = base + s[t] - c;
  if (idx == N - 1) offs[N] = base + s[t];
}

__global__ __launch_bounds__(256) void scatter_kernel(
    const int* __restrict__ src, const int* __restrict__ dst,
    const int* __restrict__ offs, int* __restrict__ cursor,
    int* __restrict__ csr, int E) {
  int e = blockIdx.x * 256 + threadIdx.x;
  if (e >= E) return;
  int d = dst[e];
  int pos = offs[d] + atomicAdd(&cursor[d], 1);
  csr[pos] = src[e];
}

// ---------------- GEMM: F[N,128] = H[N,128] @ W[128,128] -------------------
template <bool FUSE_EMBED>
__global__ __launch_bounds__(256) void gemm_kernel(
    const float* __restrict__ H, const int* __restrict__ feats,
    const float* __restrict__ ke, const float* __restrict__ ve,
    const float* __restrict__ W, float* __restrict__ F, int N) {
  __shared__ float4 sW4[128 * 32];   // 64 KB
  __shared__ float sH[32][128];      // 16 KB
  const float4* W4 = (const float4*)W;
  for (int i = threadIdx.x; i < 128 * 32; i += 256) sW4[i] = W4[i];
  int row0 = blockIdx.x * 32;
  for (int i = threadIdx.x; i < 32 * 32; i += 256) {
    int r = i >> 5, j = i & 31;
    int row = row0 + r;
    float4 v = make_float4(0.f, 0.f, 0.f, 0.f);
    if (row < N) {
      if (FUSE_EMBED) {
        int f0 = feats[2 * row], f1 = feats[2 * row + 1];
        float4 a = ((const float4*)(ke + (size_t)f0 * HID))[j];
        float4 b = ((const float4*)(ve + (size_t)f1 * HID))[j];
        v.x = fmaxf(a.x + b.x, 0.f);
        v.y = fmaxf(a.y + b.y, 0.f);
        v.z = fmaxf(a.z + b.z, 0.f);
        v.w = fmaxf(a.w + b.w, 0.f);
      } else {
        v = ((const float4*)(H + (size_t)row * HID))[j];
      }
    }
    ((float4*)&sH[r][0])[j] = v;
  }
  __syncthreads();
  int rg = threadIdx.x >> 5;
  int cg = threadIdx.x & 31;
  float4 acc0 = make_float4(0.f, 0.f, 0.f, 0.f);
  float4 acc1 = acc0, acc2 = acc0, acc3 = acc0;
#pragma unroll 4
  for (int k = 0; k < 128; ++k) {
    float4 wv = sW4[k * 32 + cg];
    float h0 = sH[rg * 4 + 0][k];
    float h1 = sH[rg * 4 + 1][k];
    float h2 = sH[rg * 4 + 2][k];
    float h3 = sH[rg * 4 + 3][k];
    acc0.x += h0 * wv.x; acc0.y += h0 * wv.y; acc0.z += h0 * wv.z; acc0.w += h0 * wv.w;
    acc1.x += h1 * wv.x; acc1.y += h1 * wv.y; acc1.z += h1 * wv.z; acc1.w += h1 * wv.w;
    acc2.x += h2 * wv.x; acc2.y += h2 * wv.y; acc2.z += h2 * wv.z; acc2.w += h2 * wv.w;
    acc3.x += h3 * wv.x; acc3.y += h3 * wv.y; acc3.z += h3 * wv.z; acc3.w += h3 * wv.w;
  }
  int r0 = row0 + rg * 4;
  if (r0 + 0 < N) ((float4*)(F + (size_t)(r0 + 0) * HID))[cg] = acc0;
  if (r0 + 1 < N) ((float4*)(F + (size_t)(r0 + 1) * HID))[cg] = acc1;
  if (r0 + 2 < N) ((float4*)(F + (size_t)(r0 + 2) * HID))[cg] = acc2;
  if (r0 + 3 < N) ((float4*)(F + (size_t)(r0 + 3) * HID))[cg] = acc3;
}

// ---------------- GATv2 layer ------------------------------------------------
// Wave = 1 node. 4 groups of 16 lanes; lane holds dims [8*l16, 8*l16+8).
// Group g processes edges beg+g, beg+g+4, ... with group-local online softmax;
// 2-stage cross-group flash merge at the end.
// logit partial uses leaky(t) = 0.6t + 0.4|t| with pre-scaled attn vectors.
__device__ __forceinline__ float dot8(
    const float4& f0, const float4& f1, const float4& fd0, const float4& fd1,
    const float4& a6_0, const float4& a6_1, const float4& a4_0, const float4& a4_1) {
  float p = 0.f, t;
  t = f0.x + fd0.x; p = fmaf(a6_0.x, t, p); p = fmaf(a4_0.x, fabsf(t), p);
  t = f0.y + fd0.y; p = fmaf(a6_0.y, t, p); p = fmaf(a4_0.y, fabsf(t), p);
  t = f0.z + fd0.z; p = fmaf(a6_0.z, t, p); p = fmaf(a4_0.z, fabsf(t), p);
  t = f0.w + fd0.w; p = fmaf(a6_0.w, t, p); p = fmaf(a4_0.w, fabsf(t), p);
  t = f1.x + fd1.x; p = fmaf(a6_1.x, t, p); p = fmaf(a4_1.x, fabsf(t), p);
  t = f1.y + fd1.y; p = fmaf(a6_1.y, t, p); p = fmaf(a4_1.y, fabsf(t), p);
  t = f1.z + fd1.z; p = fmaf(a6_1.z, t, p); p = fmaf(a4_1.z, fabsf(t), p);
  t = f1.w + fd1.w; p = fmaf(a6_1.w, t, p); p = fmaf(a4_1.w, fabsf(t), p);
  return p;
}

template <bool FUSE_CLS>
__global__ __launch_bounds__(256) void gat_kernel(
    const float* __restrict__ F, const int* __restrict__ offs,
    const int* __restrict__ csr, const float* __restrict__ attn,
    float* __restrict__ Hout, const float* __restrict__ clsw,
    float* __restrict__ out, int N) {
  int node = blockIdx.x * 4 + (threadIdx.x >> 6);
  if (node >= N) return;
  int lane = threadIdx.x & 63;
  int g = lane >> 4, l16 = lane & 15;
  const float4* F4 = (const float4*)F;
  size_t nb = (size_t)node * 32;
  float4 fd0 = F4[nb + 2 * l16];
  float4 fd1 = F4[nb + 2 * l16 + 1];
  const float4* A4 = (const float4*)attn;
  float4 av0 = A4[2 * l16], av1 = A4[2 * l16 + 1];
  float4 a6_0, a6_1, a4_0, a4_1;
  a6_0.x = 0.6f * av0.x; a6_0.y = 0.6f * av0.y; a6_0.z = 0.6f * av0.z; a6_0.w = 0.6f * av0.w;
  a6_1.x = 0.6f * av1.x; a6_1.y = 0.6f * av1.y; a6_1.z = 0.6f * av1.z; a6_1.w = 0.6f * av1.w;
  a4_0.x = 0.4f * av0.x; a4_0.y = 0.4f * av0.y; a4_0.z = 0.4f * av0.z; a4_0.w = 0.4f * av0.w;
  a4_1.x = 0.4f * av1.x; a4_1.y = 0.4f * av1.y; a4_1.z = 0.4f * av1.z; a4_1.w = 0.4f * av1.w;

  int beg = offs[node], end = offs[node + 1];
  float m = -INFINITY, l = 0.f;
  float4 acc0 = make_float4(0.f, 0.f, 0.f, 0.f), acc1 = acc0;
  int i = beg + g;
  // 2 edges per group-iteration (8 per wave-iteration in flight)
  for (; i + 4 < end; i += 8) {
    int sa = csr[i], sb = csr[i + 4];
    size_t ba = (size_t)sa * 32, bb = (size_t)sb * 32;
    float4 fa0 = F4[ba + 2 * l16], fa1 = F4[ba + 2 * l16 + 1];
    float4 fb0 = F4[bb + 2 * l16], fb1 = F4[bb + 2 * l16 + 1];
    float pa = dot8(fa0, fa1, fd0, fd1, a6_0, a6_1, a4_0, a4_1);
    float pb = dot8(fb0, fb1, fd0, fd1, a6_0, a6_1, a4_0, a4_1);
#pragma unroll
    for (int o = 1; o <= 8; o <<= 1) {
      pa += __shfl_xor(pa, o, 64);
      pb += __shfl_xor(pb, o, 64);
    }
    float mn = fmaxf(m, fmaxf(pa, pb));
    float sc = __expf(m - mn);
    float ea = __expf(pa - mn);
    float eb = __expf(pb - mn);
    l = fmaf(l, sc, ea + eb);
    acc0.x = fmaf(eb, fb0.x, fmaf(ea, fa0.x, acc0.x * sc));
    acc0.y = fmaf(eb, fb0.y, fmaf(ea, fa0.y, acc0.y * sc));
    acc0.z = fmaf(eb, fb0.z, fmaf(ea, fa0.z, acc0.z * sc));
    acc0.w = fmaf(eb, fb0.w, fmaf(ea, fa0.w, acc0.w * sc));
    acc1.x = fmaf(eb, fb1.x, fmaf(ea, fa1.x, acc1.x * sc));
    acc1.y = fmaf(eb, fb1.y, fmaf(ea, fa1.y, acc1.y * sc));
    acc1.z = fmaf(eb, fb1.z, fmaf(ea, fa1.z, acc1.z * sc));
    acc1.w = fmaf(eb, fb1.w, fmaf(ea, fa1.w, acc1.w * sc));
    m = mn;
  }
  if (i < end) {   // at most one leftover edge per group
    int s = csr[i];
    size_t bs = (size_t)s * 32;
    float4 f0 = F4[bs + 2 * l16], f1 = F4[bs + 2 * l16 + 1];
    float p = dot8(f0, f1, fd0, fd1, a6_0, a6_1, a4_0, a4_1);
#pragma unroll
    for (int o = 1; o <= 8; o <<= 1) p += __shfl_xor(p, o, 64);
    float mn = fmaxf(m, p);
    float sc = __expf(m - mn);
    float ex = __expf(p - mn);
    l = fmaf(l, sc, ex);
    acc0.x = fmaf(ex, f0.x, acc0.x * sc);
    acc0.y = fmaf(ex, f0.y, acc0.y * sc);
    acc0.z = fmaf(ex, f0.z, acc0.z * sc);
    acc0.w = fmaf(ex, f0.w, acc0.w * sc);
    acc1.x = fmaf(ex, f1.x, acc1.x * sc);
    acc1.y = fmaf(ex, f1.y, acc1.y * sc);
    acc1.z = fmaf(ex, f1.z, acc1.z * sc);
    acc1.w = fmaf(ex, f1.w, acc1.w * sc);
    m = mn;
  }
  // cross-group flash merge
  float mg = fmaxf(m, __shfl_xor(m, 16, 64));
  mg = fmaxf(mg, __shfl_xor(mg, 32, 64));
  float fsc = (m > -INFINITY) ? __expf(m - mg) : 0.f;
  float lw = l * fsc;
  acc0.x *= fsc; acc0.y *= fsc; acc0.z *= fsc; acc0.w *= fsc;
  acc1.x *= fsc; acc1.y *= fsc; acc1.z *= fsc; acc1.w *= fsc;
#pragma unroll
  for (int o = 16; o <= 32; o <<= 1) {
    lw += __shfl_xor(lw, o, 64);
    acc0.x += __shfl_xor(acc0.x, o, 64);
    acc0.y += __shfl_xor(acc0.y, o, 64);
    acc0.z += __shfl_xor(acc0.z, o, 64);
    acc0.w += __shfl_xor(acc0.w, o, 64);
    acc1.x += __shfl_xor(acc1.x, o, 64);
    acc1.y += __shfl_xor(acc1.y, o, 64);
    acc1.z += __shfl_xor(acc1.z, o, 64);
    acc1.w += __shfl_xor(acc1.w, o, 64);
  }
  float inv = (lw > 0.f) ? 1.f / lw : 0.f;
  acc0.x *= inv; acc0.y *= inv; acc0.z *= inv; acc0.w *= inv;
  acc1.x *= inv; acc1.y *= inv; acc1.z *= inv; acc1.w *= inv;

  if (!FUSE_CLS) {
    if (g == 0) {
      ((float4*)Hout)[nb + 2 * l16] = acc0;
      ((float4*)Hout)[nb + 2 * l16 + 1] = acc1;
    }
  } else {
    // classifier: group g computes output cols 4g..4g+3
    const float4* Wc4 = (const float4*)clsw;   // clsw[128][16] -> idx d*4 + c4
    int base = (8 * l16) * 4 + g;
    float4 y = make_float4(0.f, 0.f, 0.f, 0.f);
    float4 w;
    w = Wc4[base +  0]; y.x = fmaf(acc0.x, w.x, y.x); y.y = fmaf(acc0.x, w.y, y.y); y.z = fmaf(acc0.x, w.z, y.z); y.w = fmaf(acc0.x, w.w, y.w);
    w = Wc4[base +  4]; y.x = fmaf(acc0.y, w.x, y.x); y.y = fmaf(acc0.y, w.y, y.y); y.z = fmaf(acc0.y, w.z, y.z); y.w = fmaf(acc0.y, w.w, y.w);
    w = Wc4[base +  8]; y.x = fmaf(acc0.z, w.x, y.x); y.y = fmaf(acc0.z, w.y, y.y); y.z = fmaf(acc0.z, w.z, y.z); y.w = fmaf(acc0.z, w.w, y.w);
    w = Wc4[base + 12]; y.x = fmaf(acc0.w, w.x, y.x); y.y = fmaf(acc0.w, w.y, y.y); y.z = fmaf(acc0.w, w.z, y.z); y.w = fmaf(acc0.w, w.w, y.w);
    w = Wc4[base + 16]; y.x = fmaf(acc1.x, w.x, y.x); y.y = fmaf(acc1.x, w.y, y.y); y.z = fmaf(acc1.x, w.z, y.z); y.w = fmaf(acc1.x, w.w, y.w);
    w = Wc4[base + 20]; y.x = fmaf(acc1.y, w.x, y.x); y.y = fmaf(acc1.y, w.y, y.y); y.z = fmaf(acc1.y, w.z, y.z); y.w = fmaf(acc1.y, w.w, y.w);
    w = Wc4[base + 24]; y.x = fmaf(acc1.z, w.x, y.x); y.y = fmaf(acc1.z, w.y, y.y); y.z = fmaf(acc1.z, w.z, y.z); y.w = fmaf(acc1.z, w.w, y.w);
    w = Wc4[base + 28]; y.x = fmaf(acc1.w, w.x, y.x); y.y = fmaf(acc1.w, w.y, y.y); y.z = fmaf(acc1.w, w.z, y.z); y.w = fmaf(acc1.w, w.w, y.w);
#pragma unroll
    for (int o = 1; o <= 8; o <<= 1) {
      y.x += __shfl_xor(y.x, o, 64);
      y.y += __shfl_xor(y.y, o, 64);
      y.z += __shfl_xor(y.z, o, 64);
      y.w += __shfl_xor(y.w, o, 64);
    }
    if (l16 == 0) ((float4*)out)[(size_t)node * 4 + g] = y;
  }
}

// ---------------------------------------------------------------------------
extern "C" void kernel_launch(void* const* d_in, const int* in_sizes, int n_in,
                              void* d_out, int out_size, void* d_ws, size_t ws_size,
                              hipStream_t stream) {
  const int* feats     = (const int*)d_in[0];
  const int* src       = (const int*)d_in[1];
  const int* dst       = (const int*)d_in[2];
  const float* key_emb = (const float*)d_in[3];
  const float* val_emb = (const float*)d_in[4];
  const float* W1      = (const float*)d_in[5];
  const float* attn1   = (const float*)d_in[6];
  const float* W2      = (const float*)d_in[7];
  const float* attn2   = (const float*)d_in[8];
  const float* cls_w   = (const float*)d_in[9];

  int N = in_sizes[0] / 2;
  int E = in_sizes[1];
  int NB = (N + 255) / 256;

  char* ws = (char*)d_ws;
  float* fbuf  = (float*)ws;                        // N*128 f32
  float* hbuf  = fbuf + (size_t)N * HID;            // N*128 f32
  int* counts  = (int*)(hbuf + (size_t)N * HID);    // N
  int* cursor  = counts + N;                        // N
  int* offs    = cursor + N;                        // N+1
  int* csr     = offs + (N + 1);                    // E
  int* partials = csr + E;                          // 256
  int* bases    = partials + 256;                   // 256

  hipMemsetAsync(counts, 0, sizeof(int) * 2 * (size_t)N, stream);

  hist_kernel<<<(E + 255) / 256, 256, 0, stream>>>(dst, counts, E);
  partial_kernel<<<NB, 256, 0, stream>>>(counts, partials, N);
  scan2_kernel<<<1, 256, 0, stream>>>(partials, bases, NB);
  offs_kernel<<<NB, 256, 0, stream>>>(counts, bases, offs, N);
  scatter_kernel<<<(E + 255) / 256, 256, 0, stream>>>(src, dst, offs, cursor, csr, E);

  // layer 1 (embed fused into GEMM staging)
  gemm_kernel<true><<<(N + 31) / 32, 256, 0, stream>>>(
      nullptr, feats, key_emb, val_emb, W1, fbuf, N);
  gat_kernel<false><<<(N + 3) / 4, 256, 0, stream>>>(
      fbuf, offs, csr, attn1, hbuf, nullptr, nullptr, N);
  // layer 2 (+ fused classifier)
  gemm_kernel<false><<<(N + 31) / 32, 256, 0, stream>>>(
      hbuf, nullptr, nullptr, nullptr, W2, fbuf, N);
  gat_kernel<true><<<(N + 3) / 4, 256, 0, stream>>>(
      fbuf, offs, csr, attn2, nullptr, cls_w, (float*)d_out, N);
}

// Round 4
// 286.952 us; speedup vs baseline: 1.9185x; 1.0942x over previous
//
#include <hip/hip_runtime.h>
#include <math.h>

#define HID 128

// ---------------- CSR build -------------------------------------------------
// hist also records each edge's within-node rank (atomicAdd return value)
__global__ __launch_bounds__(256) void hist_kernel(
    const int* __restrict__ dst, int* __restrict__ counts,
    int* __restrict__ rank, int E) {
  int e = blockIdx.x * 256 + threadIdx.x;
  if (e < E) rank[e] = atomicAdd(&counts[dst[e]], 1);
}

__global__ __launch_bounds__(256) void partial_kernel(
    const int* __restrict__ counts, int* __restrict__ partials, int N) {
  __shared__ int s[256];
  int idx = blockIdx.x * 256 + threadIdx.x;
  s[threadIdx.x] = (idx < N) ? counts[idx] : 0;
  __syncthreads();
  for (int o = 128; o > 0; o >>= 1) {
    if (threadIdx.x < o) s[threadIdx.x] += s[threadIdx.x + o];
    __syncthreads();
  }
  if (threadIdx.x == 0) partials[blockIdx.x] = s[0];
}

__global__ __launch_bounds__(256) void scan2_kernel(
    const int* __restrict__ partials, int* __restrict__ bases, int NB) {
  __shared__ int s[256];
  int t = threadIdx.x;
  int v0 = (t < NB) ? partials[t] : 0;
  s[t] = v0;
  __syncthreads();
  for (int o = 1; o < 256; o <<= 1) {
    int v = (t >= o) ? s[t - o] : 0;
    __syncthreads();
    s[t] += v;
    __syncthreads();
  }
  bases[t] = s[t] - v0;   // exclusive
}

__global__ __launch_bounds__(256) void offs_kernel(
    const int* __restrict__ counts, const int* __restrict__ bases,
    int* __restrict__ offs, int N) {
  __shared__ int s[256];
  int t = threadIdx.x;
  int idx = blockIdx.x * 256 + t;
  int c = (idx < N) ? counts[idx] : 0;
  s[t] = c;
  __syncthreads();
  for (int o = 1; o < 256; o <<= 1) {
    int v = (t >= o) ? s[t - o] : 0;
    __syncthreads();
    s[t] += v;
    __syncthreads();
  }
  int base = bases[blockIdx.x];
  if (idx < N) offs[idx] = base + s[t] - c;
  if (idx == N - 1) offs[N] = base + s[t];
}

// atomic-free scatter: position = offs[dst] + precomputed rank
__global__ __launch_bounds__(256) void scatter_kernel(
    const int* __restrict__ src, const int* __restrict__ dst,
    const int* __restrict__ offs, const int* __restrict__ rank,
    int* __restrict__ csr, int E) {
  int e = blockIdx.x * 256 + threadIdx.x;
  if (e >= E) return;
  csr[offs[dst[e]] + rank[e]] = src[e];
}

// ---------------- GEMM: F[N,128] = H[N,128] @ W[128,128] -------------------
// grid-stride over 32-row tiles; W staged in LDS once per block.
template <bool FUSE_EMBED>
__global__ __launch_bounds__(256) void gemm_kernel(
    const float* __restrict__ H, const int* __restrict__ feats,
    const float* __restrict__ ke, const float* __restrict__ ve,
    const float* __restrict__ W, float* __restrict__ F, int N, int ntiles) {
  __shared__ float4 sW4[128 * 32];   // 64 KB, [k][col/4]
  __shared__ float sH[32][128];      // 16 KB
  const float4* W4 = (const float4*)W;
  for (int i = threadIdx.x; i < 128 * 32; i += 256) sW4[i] = W4[i];

  int rg = threadIdx.x >> 5;   // rows rg*4..rg*4+3
  int cg = threadIdx.x & 31;   // col group of 4

  for (int tile = blockIdx.x; tile < ntiles; tile += gridDim.x) {
    int row0 = tile * 32;
    __syncthreads();   // previous compute done (also covers sW4 on first iter)
    for (int i = threadIdx.x; i < 32 * 32; i += 256) {
      int r = i >> 5, j = i & 31;
      int row = row0 + r;
      float4 v = make_float4(0.f, 0.f, 0.f, 0.f);
      if (row < N) {
        if (FUSE_EMBED) {
          int f0 = feats[2 * row], f1 = feats[2 * row + 1];
          float4 a = ((const float4*)(ke + (size_t)f0 * HID))[j];
          float4 b = ((const float4*)(ve + (size_t)f1 * HID))[j];
          v.x = fmaxf(a.x + b.x, 0.f);
          v.y = fmaxf(a.y + b.y, 0.f);
          v.z = fmaxf(a.z + b.z, 0.f);
          v.w = fmaxf(a.w + b.w, 0.f);
        } else {
          v = ((const float4*)(H + (size_t)row * HID))[j];
        }
      }
      ((float4*)&sH[r][0])[j] = v;
    }
    __syncthreads();

    float4 acc0 = make_float4(0.f, 0.f, 0.f, 0.f);
    float4 acc1 = acc0, acc2 = acc0, acc3 = acc0;
#pragma unroll 8
    for (int k4 = 0; k4 < 128; k4 += 4) {
      float4 h0 = *((const float4*)&sH[rg * 4 + 0][k4]);  // broadcast reads
      float4 h1 = *((const float4*)&sH[rg * 4 + 1][k4]);
      float4 h2 = *((const float4*)&sH[rg * 4 + 2][k4]);
      float4 h3 = *((const float4*)&sH[rg * 4 + 3][k4]);
      float4 w0 = sW4[(k4 + 0) * 32 + cg];
      float4 w1 = sW4[(k4 + 1) * 32 + cg];
      float4 w2 = sW4[(k4 + 2) * 32 + cg];
      float4 w3 = sW4[(k4 + 3) * 32 + cg];
#define STEP(hh, ww)                                                           \
      acc0.x = fmaf(hh##0, ww.x, acc0.x); acc0.y = fmaf(hh##0, ww.y, acc0.y);  \
      acc0.z = fmaf(hh##0, ww.z, acc0.z); acc0.w = fmaf(hh##0, ww.w, acc0.w);  \
      acc1.x = fmaf(hh##1, ww.x, acc1.x); acc1.y = fmaf(hh##1, ww.y, acc1.y);  \
      acc1.z = fmaf(hh##1, ww.z, acc1.z); acc1.w = fmaf(hh##1, ww.w, acc1.w);  \
      acc2.x = fmaf(hh##2, ww.x, acc2.x); acc2.y = fmaf(hh##2, ww.y, acc2.y);  \
      acc2.z = fmaf(hh##2, ww.z, acc2.z); acc2.w = fmaf(hh##2, ww.w, acc2.w);  \
      acc3.x = fmaf(hh##3, ww.x, acc3.x); acc3.y = fmaf(hh##3, ww.y, acc3.y);  \
      acc3.z = fmaf(hh##3, ww.z, acc3.z); acc3.w = fmaf(hh##3, ww.w, acc3.w)
      { float hx0 = h0.x, hx1 = h1.x, hx2 = h2.x, hx3 = h3.x; STEP(hx, w0); }
      { float hx0 = h0.y, hx1 = h1.y, hx2 = h2.y, hx3 = h3.y; STEP(hx, w1); }
      { float hx0 = h0.z, hx1 = h1.z, hx2 = h2.z, hx3 = h3.z; STEP(hx, w2); }
      { float hx0 = h0.w, hx1 = h1.w, hx2 = h2.w, hx3 = h3.w; STEP(hx, w3); }
#undef STEP
    }
    int r0 = row0 + rg * 4;
    if (r0 + 0 < N) ((float4*)(F + (size_t)(r0 + 0) * HID))[cg] = acc0;
    if (r0 + 1 < N) ((float4*)(F + (size_t)(r0 + 1) * HID))[cg] = acc1;
    if (r0 + 2 < N) ((float4*)(F + (size_t)(r0 + 2) * HID))[cg] = acc2;
    if (r0 + 3 < N) ((float4*)(F + (size_t)(r0 + 3) * HID))[cg] = acc3;
  }
}

// ---------------- GATv2 layer ------------------------------------------------
// wave = node; lane holds dims (2*lane, 2*lane+1); 4 edges per iteration;
// packed butterfly reduce + single exp + bpermute broadcast.
__device__ __forceinline__ float dot2(float2 f, float2 fd, float2 a6, float2 a4) {
  float t0 = f.x + fd.x;
  float t1 = f.y + fd.y;
  float p = a6.x * t0;
  p = fmaf(a4.x, fabsf(t0), p);
  p = fmaf(a6.y, t1, p);
  p = fmaf(a4.y, fabsf(t1), p);
  return p;
}

__global__ __launch_bounds__(256) void gat_kernel(
    const float* __restrict__ F, const int* __restrict__ offs,
    const int* __restrict__ csr, const float* __restrict__ attn,
    float* __restrict__ Hout, int N) {
  int node = blockIdx.x * 4 + (threadIdx.x >> 6);
  if (node >= N) return;
  int lane = threadIdx.x & 63;
  const float2* F2 = (const float2*)F;
  float2 fd = F2[(size_t)node * 64 + lane];
  float2 av = ((const float2*)attn)[lane];
  float2 a6 = make_float2(0.6f * av.x, 0.6f * av.y);
  float2 a4 = make_float2(0.4f * av.x, 0.4f * av.y);
  // bpermute byte indices for broadcasting the 4 packed exponentials
  int ib0 = (lane & ~3) * 4;
  int ib1 = ib0 + 4, ib2 = ib0 + 8, ib3 = ib0 + 12;
  bool b1 = (lane & 1) != 0;
  bool b2 = (lane & 2) != 0;

  int beg = offs[node], end = offs[node + 1];
  float m = -INFINITY, l = 0.f;
  float2 acc = make_float2(0.f, 0.f);
  int i = beg;
  for (; i + 4 <= end; i += 4) {
    int s0 = csr[i + 0];
    int s1 = csr[i + 1];
    int s2 = csr[i + 2];
    int s3 = csr[i + 3];
    float2 f0 = F2[(size_t)s0 * 64 + lane];
    float2 f1 = F2[(size_t)s1 * 64 + lane];
    float2 f2 = F2[(size_t)s2 * 64 + lane];
    float2 f3 = F2[(size_t)s3 * 64 + lane];
    float p0 = dot2(f0, fd, a6, a4);
    float p1 = dot2(f1, fd, a6, a4);
    float p2 = dot2(f2, fd, a6, a4);
    float p3 = dot2(f3, fd, a6, a4);
    // packed reduce: stage1 (xor 1) pack edge pairs
    float u0 = p0 + __shfl_xor(p0, 1, 64);
    float u1 = p1 + __shfl_xor(p1, 1, 64);
    float u2 = p2 + __shfl_xor(p2, 1, 64);
    float u3 = p3 + __shfl_xor(p3, 1, 64);
    float q01 = b1 ? u1 : u0;
    float q23 = b1 ? u3 : u2;
    // stage2 (xor 2) pack quads
    float v01 = q01 + __shfl_xor(q01, 2, 64);
    float v23 = q23 + __shfl_xor(q23, 2, 64);
    float r = b2 ? v23 : v01;
    // stages 3-6: reduce all 4 edges simultaneously
    r += __shfl_xor(r, 4, 64);
    r += __shfl_xor(r, 8, 64);
    r += __shfl_xor(r, 16, 64);
    r += __shfl_xor(r, 32, 64);   // lane holds logit of edge (lane&3)
    // max of 4 logits (uniform across wave)
    float m4 = fmaxf(r, __shfl_xor(r, 1, 64));
    m4 = fmaxf(m4, __shfl_xor(m4, 2, 64));
    float mn = fmaxf(m, m4);
    float ex = __expf(r - mn);    // one exp for all 4 edges
    float e0 = __int_as_float(__builtin_amdgcn_ds_bpermute(ib0, __float_as_int(ex)));
    float e1 = __int_as_float(__builtin_amdgcn_ds_bpermute(ib1, __float_as_int(ex)));
    float e2 = __int_as_float(__builtin_amdgcn_ds_bpermute(ib2, __float_as_int(ex)));
    float e3 = __int_as_float(__builtin_amdgcn_ds_bpermute(ib3, __float_as_int(ex)));
    float sc = __expf(m - mn);    // first iter: exp(-inf)=0
    l = fmaf(l, sc, (e0 + e1) + (e2 + e3));
    acc.x = fmaf(e3, f3.x, fmaf(e2, f2.x, fmaf(e1, f1.x, fmaf(e0, f0.x, acc.x * sc))));
    acc.y = fmaf(e3, f3.y, fmaf(e2, f2.y, fmaf(e1, f1.y, fmaf(e0, f0.y, acc.y * sc))));
    m = mn;
  }
  for (; i < end; ++i) {   // <=3 leftover edges
    int s = csr[i];
    float2 fs = F2[(size_t)s * 64 + lane];
    float p = dot2(fs, fd, a6, a4);
#pragma unroll
    for (int o = 1; o <= 32; o <<= 1) p += __shfl_xor(p, o, 64);
    float mn = fmaxf(m, p);
    float sc = __expf(m - mn);
    float ex = __expf(p - mn);
    l = fmaf(l, sc, ex);
    acc.x = fmaf(ex, fs.x, acc.x * sc);
    acc.y = fmaf(ex, fs.y, acc.y * sc);
    m = mn;
  }
  float inv = (l > 0.f) ? 1.f / l : 0.f;
  float2 o2;
  o2.x = acc.x * inv;
  o2.y = acc.y * inv;
  ((float2*)Hout)[(size_t)node * 64 + lane] = o2;
}

// ---------------- classifier: out[N,16] = H @ cls_w ------------------------
__global__ __launch_bounds__(256) void classify_kernel(
    const float* __restrict__ H, const float* __restrict__ Wc,
    float* __restrict__ out, int N) {
  __shared__ float sW[HID * 16];     // 8 KB
  __shared__ float sH[16][132];      // padded
  for (int i = threadIdx.x; i < HID * 16; i += 256) sW[i] = Wc[i];
  int row0 = blockIdx.x * 16;
  for (int i = threadIdx.x; i < 16 * 32; i += 256) {
    int r = i >> 5, j = i & 31;
    int row = row0 + r;
    float4 v = make_float4(0.f, 0.f, 0.f, 0.f);
    if (row < N) v = ((const float4*)(H + (size_t)row * HID))[j];
    ((float4*)&sH[r][0])[j] = v;
  }
  __syncthreads();
  int r = threadIdx.x >> 4;
  int c = threadIdx.x & 15;
  float acc = 0.f;
#pragma unroll 8
  for (int k = 0; k < HID; ++k) acc = fmaf(sH[r][k], sW[k * 16 + c], acc);
  int row = row0 + r;
  if (row < N) out[(size_t)row * 16 + c] = acc;
}

// ---------------------------------------------------------------------------
extern "C" void kernel_launch(void* const* d_in, const int* in_sizes, int n_in,
                              void* d_out, int out_size, void* d_ws, size_t ws_size,
                              hipStream_t stream) {
  const int* feats     = (const int*)d_in[0];
  const int* src       = (const int*)d_in[1];
  const int* dst       = (const int*)d_in[2];
  const float* key_emb = (const float*)d_in[3];
  const float* val_emb = (const float*)d_in[4];
  const float* W1      = (const float*)d_in[5];
  const float* attn1   = (const float*)d_in[6];
  const float* W2      = (const float*)d_in[7];
  const float* attn2   = (const float*)d_in[8];
  const float* cls_w   = (const float*)d_in[9];

  int N = in_sizes[0] / 2;
  int E = in_sizes[1];
  int NB = (N + 255) / 256;
  int ntiles = (N + 31) / 32;

  char* ws = (char*)d_ws;
  float* fbuf   = (float*)ws;                        // N*128 f32
  float* hbuf   = fbuf + (size_t)N * HID;            // N*128 f32
  int* counts   = (int*)(hbuf + (size_t)N * HID);    // N
  int* offs     = counts + N;                        // N+1
  int* rank     = offs + (N + 1);                    // E
  int* csr      = rank + E;                          // E
  int* partials = csr + E;                           // 256
  int* bases    = partials + 256;                    // 256

  hipMemsetAsync(counts, 0, sizeof(int) * (size_t)N, stream);

  hist_kernel<<<(E + 255) / 256, 256, 0, stream>>>(dst, counts, rank, E);
  partial_kernel<<<NB, 256, 0, stream>>>(counts, partials, N);
  scan2_kernel<<<1, 256, 0, stream>>>(partials, bases, NB);
  offs_kernel<<<NB, 256, 0, stream>>>(counts, bases, offs, N);
  scatter_kernel<<<(E + 255) / 256, 256, 0, stream>>>(src, dst, offs, rank, csr, E);

  // layer 1 (embed fused into GEMM staging)
  gemm_kernel<true><<<512, 256, 0, stream>>>(
      nullptr, feats, key_emb, val_emb, W1, fbuf, N, ntiles);
  gat_kernel<<<(N + 3) / 4, 256, 0, stream>>>(fbuf, offs, csr, attn1, hbuf, N);
  // layer 2
  gemm_kernel<false><<<512, 256, 0, stream>>>(
      hbuf, nullptr, nullptr, nullptr, W2, fbuf, N, ntiles);
  gat_kernel<<<(N + 3) / 4, 256, 0, stream>>>(fbuf, offs, csr, attn2, hbuf, N);

  classify_kernel<<<(N + 15) / 16, 256, 0, stream>>>(hbuf, cls_w, (float*)d_out, N);
}

// Round 6
// 283.887 us; speedup vs baseline: 1.9392x; 1.0108x over previous
//
#include <hip/hip_runtime.h>
#include <math.h>

#define HID 128

// ---------------- CSR build (padded to 4-edge quads) ------------------------
__global__ __launch_bounds__(256) void hist_kernel(
    const int* __restrict__ dst, int* __restrict__ counts,
    int* __restrict__ rank, int E) {
  int e = blockIdx.x * 256 + threadIdx.x;
  if (e < E) rank[e] = atomicAdd(&counts[dst[e]], 1);
}

__global__ __launch_bounds__(256) void partial_kernel(
    const int* __restrict__ counts, int* __restrict__ partials, int N) {
  __shared__ int s[256];
  int idx = blockIdx.x * 256 + threadIdx.x;
  s[threadIdx.x] = (idx < N) ? ((counts[idx] + 3) & ~3) : 0;
  __syncthreads();
  for (int o = 128; o > 0; o >>= 1) {
    if (threadIdx.x < o) s[threadIdx.x] += s[threadIdx.x + o];
    __syncthreads();
  }
  if (threadIdx.x == 0) partials[blockIdx.x] = s[0];
}

__global__ __launch_bounds__(256) void scan2_kernel(
    const int* __restrict__ partials, int* __restrict__ bases, int NB) {
  __shared__ int s[256];
  int t = threadIdx.x;
  int v0 = (t < NB) ? partials[t] : 0;
  s[t] = v0;
  __syncthreads();
  for (int o = 1; o < 256; o <<= 1) {
    int v = (t >= o) ? s[t - o] : 0;
    __syncthreads();
    s[t] += v;
    __syncthreads();
  }
  bases[t] = s[t] - v0;   // exclusive
}

__global__ __launch_bounds__(256) void offs_kernel(
    const int* __restrict__ counts, const int* __restrict__ bases,
    int* __restrict__ offs, int N) {
  __shared__ int s[256];
  int t = threadIdx.x;
  int idx = blockIdx.x * 256 + t;
  int c = (idx < N) ? ((counts[idx] + 3) & ~3) : 0;
  s[t] = c;
  __syncthreads();
  for (int o = 1; o < 256; o <<= 1) {
    int v = (t >= o) ? s[t - o] : 0;
    __syncthreads();
    s[t] += v;
    __syncthreads();
  }
  int base = bases[blockIdx.x];
  if (idx < N) offs[idx] = base + s[t] - c;
  if (idx == N - 1) offs[N] = base + s[t];
}

__global__ __launch_bounds__(256) void scatter_kernel(
    const int* __restrict__ src, const int* __restrict__ dst,
    const int* __restrict__ offs, const int* __restrict__ rank,
    int* __restrict__ csr, int E) {
  int e = blockIdx.x * 256 + threadIdx.x;
  if (e >= E) return;
  csr[offs[dst[e]] + rank[e]] = src[e];
}

// fill pad slots (deg..paddeg) with node 0 (contribution nulled by -inf logit)
__global__ __launch_bounds__(256) void pad_kernel(
    const int* __restrict__ counts, const int* __restrict__ offs,
    int* __restrict__ csr, int N) {
  int n = blockIdx.x * 256 + threadIdx.x;
  if (n >= N) return;
  int deg = counts[n];
  int pad = (deg + 3) & ~3;
  int beg = offs[n];
  for (int k = deg; k < pad; ++k) csr[beg + k] = 0;
}

// ---------------- GEMM: F[N,128] = H[N,128] @ W[128,128] -------------------
template <bool FUSE_EMBED>
__global__ __launch_bounds__(256) void gemm_kernel(
    const float* __restrict__ H, const int* __restrict__ feats,
    const float* __restrict__ ke, const float* __restrict__ ve,
    const float* __restrict__ W, float* __restrict__ F, int N, int ntiles) {
  __shared__ float4 sW4[128 * 32];   // 64 KB, [k][col/4]
  __shared__ float sH[32][128];      // 16 KB
  const float4* W4 = (const float4*)W;
  for (int i = threadIdx.x; i < 128 * 32; i += 256) sW4[i] = W4[i];

  int rg = threadIdx.x >> 5;
  int cg = threadIdx.x & 31;

  for (int tile = blockIdx.x; tile < ntiles; tile += gridDim.x) {
    int row0 = tile * 32;
    __syncthreads();
    for (int i = threadIdx.x; i < 32 * 32; i += 256) {
      int r = i >> 5, j = i & 31;
      int row = row0 + r;
      float4 v = make_float4(0.f, 0.f, 0.f, 0.f);
      if (row < N) {
        if (FUSE_EMBED) {
          int f0 = feats[2 * row], f1 = feats[2 * row + 1];
          float4 a = ((const float4*)(ke + (size_t)f0 * HID))[j];
          float4 b = ((const float4*)(ve + (size_t)f1 * HID))[j];
          v.x = fmaxf(a.x + b.x, 0.f);
          v.y = fmaxf(a.y + b.y, 0.f);
          v.z = fmaxf(a.z + b.z, 0.f);
          v.w = fmaxf(a.w + b.w, 0.f);
        } else {
          v = ((const float4*)(H + (size_t)row * HID))[j];
        }
      }
      ((float4*)&sH[r][0])[j] = v;
    }
    __syncthreads();

    float4 acc0 = make_float4(0.f, 0.f, 0.f, 0.f);
    float4 acc1 = acc0, acc2 = acc0, acc3 = acc0;
#pragma unroll 8
    for (int k4 = 0; k4 < 128; k4 += 4) {
      float4 h0 = *((const float4*)&sH[rg * 4 + 0][k4]);
      float4 h1 = *((const float4*)&sH[rg * 4 + 1][k4]);
      float4 h2 = *((const float4*)&sH[rg * 4 + 2][k4]);
      float4 h3 = *((const float4*)&sH[rg * 4 + 3][k4]);
      float4 w0 = sW4[(k4 + 0) * 32 + cg];
      float4 w1 = sW4[(k4 + 1) * 32 + cg];
      float4 w2 = sW4[(k4 + 2) * 32 + cg];
      float4 w3 = sW4[(k4 + 3) * 32 + cg];
#define STEP(hh, ww)                                                           \
      acc0.x = fmaf(hh##0, ww.x, acc0.x); acc0.y = fmaf(hh##0, ww.y, acc0.y);  \
      acc0.z = fmaf(hh##0, ww.z, acc0.z); acc0.w = fmaf(hh##0, ww.w, acc0.w);  \
      acc1.x = fmaf(hh##1, ww.x, acc1.x); acc1.y = fmaf(hh##1, ww.y, acc1.y);  \
      acc1.z = fmaf(hh##1, ww.z, acc1.z); acc1.w = fmaf(hh##1, ww.w, acc1.w);  \
      acc2.x = fmaf(hh##2, ww.x, acc2.x); acc2.y = fmaf(hh##2, ww.y, acc2.y);  \
      acc2.z = fmaf(hh##2, ww.z, acc2.z); acc2.w = fmaf(hh##2, ww.w, acc2.w);  \
      acc3.x = fmaf(hh##3, ww.x, acc3.x); acc3.y = fmaf(hh##3, ww.y, acc3.y);  \
      acc3.z = fmaf(hh##3, ww.z, acc3.z); acc3.w = fmaf(hh##3, ww.w, acc3.w)
      { float hx0 = h0.x, hx1 = h1.x, hx2 = h2.x, hx3 = h3.x; STEP(hx, w0); }
      { float hx0 = h0.y, hx1 = h1.y, hx2 = h2.y, hx3 = h3.y; STEP(hx, w1); }
      { float hx0 = h0.z, hx1 = h1.z, hx2 = h2.z, hx3 = h3.z; STEP(hx, w2); }
      { float hx0 = h0.w, hx1 = h1.w, hx2 = h2.w, hx3 = h3.w; STEP(hx, w3); }
#undef STEP
    }
    int r0 = row0 + rg * 4;
    if (r0 + 0 < N) ((float4*)(F + (size_t)(r0 + 0) * HID))[cg] = acc0;
    if (r0 + 1 < N) ((float4*)(F + (size_t)(r0 + 1) * HID))[cg] = acc1;
    if (r0 + 2 < N) ((float4*)(F + (size_t)(r0 + 2) * HID))[cg] = acc2;
    if (r0 + 3 < N) ((float4*)(F + (size_t)(r0 + 3) * HID))[cg] = acc3;
  }
}

// ---------------- GATv2 layer ------------------------------------------------
// 32-lane group = 1 node (2 nodes/wave); lane holds dims 4q..4q+3 (float4).
// 4 edges/iteration via int4 csr quad (padded); packed butterfly reduce,
// single exp + bpermute broadcast; 1-deep software pipeline on gathers.
__device__ __forceinline__ float dot4f(const float4& f, const float4& fd,
                                       const float4& a6, const float4& a4) {
  float t, p;
  t = f.x + fd.x; p = a6.x * t;         p = fmaf(a4.x, fabsf(t), p);
  t = f.y + fd.y; p = fmaf(a6.y, t, p); p = fmaf(a4.y, fabsf(t), p);
  t = f.z + fd.z; p = fmaf(a6.z, t, p); p = fmaf(a4.z, fabsf(t), p);
  t = f.w + fd.w; p = fmaf(a6.w, t, p); p = fmaf(a4.w, fabsf(t), p);
  return p;
}

__global__ __launch_bounds__(256) void gat_kernel(
    const float* __restrict__ F, const int* __restrict__ offs,
    const int* __restrict__ counts, const int* __restrict__ csr,
    const float* __restrict__ attn, float* __restrict__ Hout, int N) {
  int node = blockIdx.x * 8 + (threadIdx.x >> 5);
  if (node >= N) return;
  int q = threadIdx.x & 31;        // lane within group
  int lane = threadIdx.x & 63;
  const float4* F4 = (const float4*)F;
  float4 fd = F4[(size_t)node * 32 + q];
  float4 av = ((const float4*)attn)[q];
  float4 a6, a4;
  a6.x = 0.6f * av.x; a6.y = 0.6f * av.y; a6.z = 0.6f * av.z; a6.w = 0.6f * av.w;
  a4.x = 0.4f * av.x; a4.y = 0.4f * av.y; a4.z = 0.4f * av.z; a4.w = 0.4f * av.w;
  int ib = (lane & 32) << 2;       // bpermute byte base of this group
  bool b1 = (q & 1) != 0;
  bool b2 = (q & 2) != 0;

  int beg = offs[node];
  int end = beg + counts[node];    // true (unpadded) end
  float m = -INFINITY, l = 0.f;
  float4 acc = make_float4(0.f, 0.f, 0.f, 0.f);

  if (beg < end) {
    int i = beg;
    int4 sv = *(const int4*)(csr + i);    // padded segment: always safe
    float4 f0 = F4[(size_t)sv.x * 32 + q];
    float4 f1 = F4[(size_t)sv.y * 32 + q];
    float4 f2 = F4[(size_t)sv.z * 32 + q];
    float4 f3 = F4[(size_t)sv.w * 32 + q];
    while (true) {
      bool more = (i + 4 < end);
      int4 nv;
      float4 g0, g1, g2, g3;
      if (more) {                          // prefetch next quad
        nv = *(const int4*)(csr + i + 4);
        g0 = F4[(size_t)nv.x * 32 + q];
        g1 = F4[(size_t)nv.y * 32 + q];
        g2 = F4[(size_t)nv.z * 32 + q];
        g3 = F4[(size_t)nv.w * 32 + q];
      }
      float p0 = dot4f(f0, fd, a6, a4);    // edge i+0 always valid
      float p1 = (i + 1 < end) ? dot4f(f1, fd, a6, a4) : -INFINITY;
      float p2 = (i + 2 < end) ? dot4f(f2, fd, a6, a4) : -INFINITY;
      float p3 = (i + 3 < end) ? dot4f(f3, fd, a6, a4) : -INFINITY;
      // packed butterfly (stays within the 32-lane group; masks <= 16)
      float u0 = p0 + __shfl_xor(p0, 1, 64);
      float u1 = p1 + __shfl_xor(p1, 1, 64);
      float u2 = p2 + __shfl_xor(p2, 1, 64);
      float u3 = p3 + __shfl_xor(p3, 1, 64);
      float q01 = b1 ? u1 : u0;
      float q23 = b1 ? u3 : u2;
      float v01 = q01 + __shfl_xor(q01, 2, 64);
      float v23 = q23 + __shfl_xor(q23, 2, 64);
      float r = b2 ? v23 : v01;
      r += __shfl_xor(r, 4, 64);
      r += __shfl_xor(r, 8, 64);
      r += __shfl_xor(r, 16, 64);          // lane holds logit of edge (q&3)
      float m4 = fmaxf(r, __shfl_xor(r, 1, 64));
      m4 = fmaxf(m4, __shfl_xor(m4, 2, 64));
      float mn = fmaxf(m, m4);
      float ex = __expf(r - mn);           // one exp covers 4 edges
      float e0 = __int_as_float(__builtin_amdgcn_ds_bpermute(ib, __float_as_int(ex)));
      float e1 = __int_as_float(__builtin_amdgcn_ds_bpermute(ib + 4, __float_as_int(ex)));
      float e2 = __int_as_float(__builtin_amdgcn_ds_bpermute(ib + 8, __float_as_int(ex)));
      float e3 = __int_as_float(__builtin_amdgcn_ds_bpermute(ib + 12, __float_as_int(ex)));
      float sc = __expf(m - mn);           // first iter: exp(-inf)=0
      l = fmaf(l, sc, (e0 + e1) + (e2 + e3));
      acc.x = fmaf(e3, f3.x, fmaf(e2, f2.x, fmaf(e1, f1.x, fmaf(e0, f0.x, acc.x * sc))));
      acc.y = fmaf(e3, f3.y, fmaf(e2, f2.y, fmaf(e1, f1.y, fmaf(e0, f0.y, acc.y * sc))));
      acc.z = fmaf(e3, f3.z, fmaf(e2, f2.z, fmaf(e1, f1.z, fmaf(e0, f0.z, acc.z * sc))));
      acc.w = fmaf(e3, f3.w, fmaf(e2, f2.w, fmaf(e1, f1.w, fmaf(e0, f0.w, acc.w * sc))));
      m = mn;
      if (!more) break;
      i += 4;
      sv = nv;
      f0 = g0; f1 = g1; f2 = g2; f3 = g3;
    }
  }
  float inv = (l > 0.f) ? 1.f / l : 0.f;
  acc.x *= inv; acc.y *= inv; acc.z *= inv; acc.w *= inv;
  ((float4*)Hout)[(size_t)node * 32 + q] = acc;
}

// ---------------- classifier: out[N,16] = H @ cls_w ------------------------
__global__ __launch_bounds__(256) void classify_kernel(
    const float* __restrict__ H, const float* __restrict__ Wc,
    float* __restrict__ out, int N) {
  __shared__ float sW[HID * 16];     // 8 KB
  __shared__ float sH[16][132];      // padded
  for (int i = threadIdx.x; i < HID * 16; i += 256) sW[i] = Wc[i];
  int row0 = blockIdx.x * 16;
  for (int i = threadIdx.x; i < 16 * 32; i += 256) {
    int r = i >> 5, j = i & 31;
    int row = row0 + r;
    float4 v = make_float4(0.f, 0.f, 0.f, 0.f);
    if (row < N) v = ((const float4*)(H + (size_t)row * HID))[j];
    ((float4*)&sH[r][0])[j] = v;
  }
  __syncthreads();
  int r = threadIdx.x >> 4;
  int c = threadIdx.x & 15;
  float acc = 0.f;
#pragma unroll 8
  for (int k = 0; k < HID; ++k) acc = fmaf(sH[r][k], sW[k * 16 + c], acc);
  int row = row0 + r;
  if (row < N) out[(size_t)row * 16 + c] = acc;
}

// ---------------------------------------------------------------------------
extern "C" void kernel_launch(void* const* d_in, const int* in_sizes, int n_in,
                              void* d_out, int out_size, void* d_ws, size_t ws_size,
                              hipStream_t stream) {
  const int* feats     = (const int*)d_in[0];
  const int* src       = (const int*)d_in[1];
  const int* dst       = (const int*)d_in[2];
  const float* key_emb = (const float*)d_in[3];
  const float* val_emb = (const float*)d_in[4];
  const float* W1      = (const float*)d_in[5];
  const float* attn1   = (const float*)d_in[6];
  const float* W2      = (const float*)d_in[7];
  const float* attn2   = (const float*)d_in[8];
  const float* cls_w   = (const float*)d_in[9];

  int N = in_sizes[0] / 2;
  int E = in_sizes[1];
  int NB = (N + 255) / 256;
  int ntiles = (N + 31) / 32;

  // 16B-aligned workspace layout (all extents rounded to multiples of 4 ints)
  int Np = (N + 3) & ~3;
  int Ep = (E + 3) & ~3;
  char* ws = (char*)d_ws;
  float* fbuf   = (float*)ws;                        // N*128 f32
  float* hbuf   = fbuf + (size_t)Np * HID;           // N*128 f32
  int* counts   = (int*)(hbuf + (size_t)Np * HID);   // Np
  int* offs     = counts + Np;                       // Np+4 (holds N+1)
  int* rank     = offs + Np + 4;                     // Ep
  int* csr      = rank + Ep;                         // Ep + 4*Np (padded)
  int* partials = csr + Ep + 4 * (size_t)Np;         // 256
  int* bases    = partials + 256;                    // 256

  hipMemsetAsync(counts, 0, sizeof(int) * (size_t)Np, stream);

  hist_kernel<<<(E + 255) / 256, 256, 0, stream>>>(dst, counts, rank, E);
  partial_kernel<<<NB, 256, 0, stream>>>(counts, partials, N);
  scan2_kernel<<<1, 256, 0, stream>>>(partials, bases, NB);
  offs_kernel<<<NB, 256, 0, stream>>>(counts, bases, offs, N);
  scatter_kernel<<<(E + 255) / 256, 256, 0, stream>>>(src, dst, offs, rank, csr, E);
  pad_kernel<<<NB, 256, 0, stream>>>(counts, offs, csr, N);

  // layer 1 (embed fused into GEMM staging)
  gemm_kernel<true><<<512, 256, 0, stream>>>(
      nullptr, feats, key_emb, val_emb, W1, fbuf, N, ntiles);
  gat_kernel<<<(N + 7) / 8, 256, 0, stream>>>(
      fbuf, offs, counts, csr, attn1, hbuf, N);
  // layer 2
  gemm_kernel<false><<<512, 256, 0, stream>>>(
      hbuf, nullptr, nullptr, nullptr, W2, fbuf, N, ntiles);
  gat_kernel<<<(N + 7) / 8, 256, 0, stream>>>(
      fbuf, offs, counts, csr, attn2, hbuf, N);

  classify_kernel<<<(N + 15) / 16, 256, 0, stream>>>(hbuf, cls_w, (float*)d_out, N);
}